// Round 6
// baseline (175.907 us; speedup 1.0000x reference)
//
#include <hip/hip_runtime.h>

#define EDIM 128
#define MDIM 8
#define ADIM 64
#define NFR  50
#define NCOL (NFR * MDIM)   // 400

typedef __attribute__((ext_vector_type(8))) short short8;
typedef __attribute__((ext_vector_type(4))) float f32x4;

__device__ __forceinline__ float waveReduceSum(float v) {
    #pragma unroll
    for (int s = 32; s >= 1; s >>= 1) v += __shfl_xor(v, s, 64);
    return v;
}
__device__ __forceinline__ short f2bf(float x) {
    unsigned u = __float_as_uint(x);
    u += 0x7FFFu + ((u >> 16) & 1u);
    return (short)(u >> 16);
}

// k0: prepack static A-fragments (16x16x32 bf16: row=lane&15, k=(lane>>4)*8+j)
__global__ __launch_bounds__(256)
void k0_prep(const float* __restrict__ WA, const float* __restrict__ Mem,
             const float* __restrict__ Key,
             short* __restrict__ WATf, short* __restrict__ MemTf,
             short* __restrict__ KeyTf)
{
    int t = blockIdx.x * 256 + threadIdx.x;
    int lane = t & 63, c = lane & 15, g = (lane >> 4) & 3;
    short8 v = {0, 0, 0, 0, 0, 0, 0, 0};
    if (t < 1024) {                       // WATf: frag = Ma*4+Kt
        int frag = t >> 6, Ma = frag >> 2, Kt = frag & 3;
        int a = Ma * 16 + c;
        #pragma unroll
        for (int j = 0; j < 8; ++j) {
            int e = Kt * 32 + g * 8 + j;
            v[j] = f2bf(WA[(size_t)e * ADIM + a]);
        }
        *(short8*)(WATf + (size_t)t * 8) = v;
    } else if (t < 1536) {                // MemTf
        int i = t - 1024, Mt = i >> 6;
        int e = Mt * 16 + c;
        #pragma unroll
        for (int j = 0; j < 8; ++j) {
            int k = g * 8 + j;
            v[j] = (k < MDIM) ? f2bf(Mem[(size_t)k * EDIM + e]) : (short)0;
        }
        *(short8*)(MemTf + (size_t)i * 8) = v;
    } else if (t < 1792) {                // KeyTf
        int i = t - 1536, Kt = i >> 6;
        #pragma unroll
        for (int j = 0; j < 8; ++j) {
            int e = Kt * 32 + g * 8 + j;
            v[j] = (c < MDIM) ? f2bf(Key[(size_t)e * MDIM + c]) : (short)0;
        }
        *(short8*)(KeyTf + (size_t)i * 8) = v;
    }
}

// k1: att^T[m][f] = Key^T(16m x 128e) x cross^T(128e x 64f), cross in regs
__global__ __launch_bounds__(256, 4)
void k1_attkey(const int* __restrict__ input_u, const int* __restrict__ input_uf,
               const float* __restrict__ uidW, const short* __restrict__ KeyTf,
               float* __restrict__ att_key, int user_num)
{
    const int b = blockIdx.x, t = threadIdx.x, w = t >> 6, l = t & 63;
    const int c = l & 15, g = l >> 4;
    __shared__ float uidn[EDIM];
    __shared__ float redW[4];
    __shared__ int ufL[64];

    if (t < 64) ufL[t] = (t < NFR) ? input_uf[(size_t)b * NFR + t] : user_num;
    const int u = input_u[b];
    float x = (t < EDIM) ? uidW[(size_t)u * EDIM + t] : 0.f;
    float ss = waveReduceSum(x * x);
    if (l == 0) redW[w] = ss;
    __syncthreads();
    float uinv = 1.0f / fmaxf(sqrtf(redW[0] + redW[1] + redW[2] + redW[3]), 1e-12f);
    if (t < EDIM) uidn[t] = x * uinv;
    __syncthreads();

    const int f = w * 16 + c;
    const int fid = ufL[f];
    const float fn = (f < NFR && fid != user_num) ? 1.0f : 0.0f;
    const float* fp = uidW + (size_t)fid * EDIM;

    float4 fe[4][2];
    #pragma unroll
    for (int Kt = 0; Kt < 4; ++Kt) {
        fe[Kt][0] = *(const float4*)(fp + Kt * 32 + g * 8);
        fe[Kt][1] = *(const float4*)(fp + Kt * 32 + g * 8 + 4);
    }
    float fss = 0.f;
    #pragma unroll
    for (int Kt = 0; Kt < 4; ++Kt)
        #pragma unroll
        for (int h = 0; h < 2; ++h) {
            float4 q = fe[Kt][h];
            fss += q.x * q.x + q.y * q.y + q.z * q.z + q.w * q.w;
        }
    fss += __shfl_xor(fss, 16, 64);
    fss += __shfl_xor(fss, 32, 64);
    const float inv2 = fn / fmaxf(sqrtf(fss), 1e-12f);

    f32x4 acc = {0.f, 0.f, 0.f, 0.f};
    #pragma unroll
    for (int Kt = 0; Kt < 4; ++Kt) {
        float4 un0 = *(const float4*)&uidn[Kt * 32 + g * 8];
        float4 un1 = *(const float4*)&uidn[Kt * 32 + g * 8 + 4];
        short8 bf;
        bf[0] = f2bf(un0.x * fe[Kt][0].x * inv2);
        bf[1] = f2bf(un0.y * fe[Kt][0].y * inv2);
        bf[2] = f2bf(un0.z * fe[Kt][0].z * inv2);
        bf[3] = f2bf(un0.w * fe[Kt][0].w * inv2);
        bf[4] = f2bf(un1.x * fe[Kt][1].x * inv2);
        bf[5] = f2bf(un1.y * fe[Kt][1].y * inv2);
        bf[6] = f2bf(un1.z * fe[Kt][1].z * inv2);
        bf[7] = f2bf(un1.w * fe[Kt][1].w * inv2);
        short8 af = *(const short8*)(KeyTf + (size_t)(Kt * 64 + l) * 8);
        acc = __builtin_amdgcn_mfma_f32_16x16x32_bf16(af, bf, acc, 0, 0, 0);
    }
    if (f < NFR && g < 2) {
        float4 st = {acc[0], acc[1], acc[2], acc[3]};
        *(float4*)&att_key[(size_t)b * NCOL + f * MDIM + g * 4] = st;
    }
}

// k2a: per (row-chunk, col-group): partial (max, sumexp) per column.
__global__ __launch_bounds__(256)
void k2a_stats(const float* __restrict__ ak,
               float* __restrict__ Pm, float* __restrict__ Ps, int B)
{
    const int cg = blockIdx.x;
    const int rc = blockIdx.y;
    const int t = threadIdx.x;
    const int c = t & 15, r = t >> 4;
    const int col = cg * 16 + c;
    const int base = rc * (B >> 4);

    float x[16];
    #pragma unroll
    for (int k = 0; k < 16; ++k)
        x[k] = ak[(size_t)(base + k * 16 + r) * NCOL + col];
    float m = x[0];
    #pragma unroll
    for (int k = 1; k < 16; ++k) m = fmaxf(m, x[k]);
    float s = 0.f;
    #pragma unroll
    for (int k = 0; k < 16; ++k) s += __expf(x[k] - m);

    __shared__ float mL[16][17], sL[16][17];
    mL[r][c] = m; sL[r][c] = s;
    __syncthreads();
    if (t < 16) {
        float M = mL[0][t];
        #pragma unroll
        for (int rr = 1; rr < 16; ++rr) M = fmaxf(M, mL[rr][t]);
        float S = 0.f;
        #pragma unroll
        for (int rr = 0; rr < 16; ++rr) S += sL[rr][t] * __expf(mL[rr][t] - M);
        Pm[rc * NCOL + cg * 16 + t] = M;
        Ps[rc * NCOL + cg * 16 + t] = S;
    }
}

// k3: amL (k2b fused) -> f1^T MFMA -> f2 regs -> per-wave repack -> h^T MFMA
//     (+iid row tile => y_f) -> p fold -> j -> score
__global__ __launch_bounds__(256, 4)
void k3_final(const int* __restrict__ input_u, const int* __restrict__ input_i,
              const int* __restrict__ input_uf, const float* __restrict__ uidW,
              const float* __restrict__ iidW, const float* __restrict__ i_bias,
              const short* __restrict__ WATf, const short* __restrict__ MemTf,
              const float* __restrict__ BA, const float* __restrict__ U_omega,
              const float* __restrict__ att_key,
              const float* __restrict__ Pm, const float* __restrict__ Ps,
              float* __restrict__ out, int user_num)
{
    const int b = blockIdx.x, t = threadIdx.x, w = t >> 6, l = t & 63;
    const int c = l & 15, g = l >> 4;
    __shared__ short WATs[16 * 64 * 8];   // 16 KB
    __shared__ short f2s[4][4 * 64 * 8];  // 16 KB
    __shared__ float amL[512];
    __shared__ float uidL[EDIM], iidL[EDIM];
    __shared__ float baL[ADIM], uoL[ADIM];
    __shared__ int ufL[64];
    __shared__ float sjW[4], syW[4];

    if (t < 64) ufL[t] = (t < NFR) ? input_uf[(size_t)b * NFR + t] : user_num;
    __syncthreads();

    const int u = input_u[b];
    const int ii = input_i[b];
    if (t < EDIM) {
        uidL[t] = uidW[(size_t)u * EDIM + t];
        iidL[t] = iidW[(size_t)ii * EDIM + t];
    }
    if (t < ADIM) { baL[t] = BA[t]; uoL[t] = U_omega[t]; }

    {   // stage WA^T frags
        const uint4* src = (const uint4*)WATf;
        uint4* dst = (uint4*)WATs;
        #pragma unroll
        for (int i = 0; i < 4; ++i) dst[t + 256 * i] = src[t + 256 * i];
    }

    const int f = w * 16 + c;
    const int fid = ufL[f];
    const float fn = (f < NFR && fid != user_num) ? 1.0f : 0.0f;
    float4 fe4[8];
    {
        const float* fp = uidW + (size_t)fid * EDIM;
        #pragma unroll
        for (int Mt = 0; Mt < 8; ++Mt)
            fe4[Mt] = *(const float4*)(fp + Mt * 16 + g * 4);
    }

    for (int i = t; i < 512; i += 256) {
        float amv = 0.f;
        if (i < NCOL) {
            float M = -3.4e38f;
            #pragma unroll
            for (int rc = 0; rc < 16; ++rc) M = fmaxf(M, Pm[rc * NCOL + i]);
            float S = 0.f;
            #pragma unroll
            for (int rc = 0; rc < 16; ++rc)
                S += Ps[rc * NCOL + i] * __expf(Pm[rc * NCOL + i] - M);
            float ak = att_key[(size_t)b * NCOL + i];
            if (ufL[i >> 3] != user_num) amv = __expf(ak - M) / S;
        }
        amL[i] = amv;
    }
    __syncthreads();

    short8 amf = {0, 0, 0, 0, 0, 0, 0, 0};
    if (g == 0) {
        float4 a0 = *(const float4*)&amL[f * 8];
        float4 a1 = *(const float4*)&amL[f * 8 + 4];
        amf[0] = f2bf(a0.x); amf[1] = f2bf(a0.y);
        amf[2] = f2bf(a0.z); amf[3] = f2bf(a0.w);
        amf[4] = f2bf(a1.x); amf[5] = f2bf(a1.y);
        amf[6] = f2bf(a1.z); amf[7] = f2bf(a1.w);
    }

    f32x4 C1[8];
    #pragma unroll
    for (int Mt = 0; Mt < 8; ++Mt) {
        short8 af = *(const short8*)(MemTf + (size_t)(Mt * 64 + l) * 8);
        f32x4 z = {0.f, 0.f, 0.f, 0.f};
        C1[Mt] = __builtin_amdgcn_mfma_f32_16x16x32_bf16(af, amf, z, 0, 0, 0);
    }

    #pragma unroll
    for (int Mt = 0; Mt < 8; ++Mt) {
        float q0 = C1[Mt][0] * fe4[Mt].x * fn;
        float q1 = C1[Mt][1] * fe4[Mt].y * fn;
        float q2 = C1[Mt][2] * fe4[Mt].z * fn;
        float q3 = C1[Mt][3] * fe4[Mt].w * fn;
        unsigned d0 = ((unsigned)(unsigned short)f2bf(q0)) |
                      (((unsigned)(unsigned short)f2bf(q1)) << 16);
        unsigned d1 = ((unsigned)(unsigned short)f2bf(q2)) |
                      (((unsigned)(unsigned short)f2bf(q3)) << 16);
        int lane2 = ((Mt & 1) * 2 + (g >> 1)) * 16 + c;
        int off = ((Mt >> 1) * 64 + lane2) * 8 + (g & 1) * 4;
        uint2 dd = {d0, d1};
        *(uint2*)&f2s[w][off] = dd;
    }

    f32x4 C2[4], C3 = {0.f, 0.f, 0.f, 0.f};
    #pragma unroll
    for (int Ma = 0; Ma < 4; ++Ma) C2[Ma] = (f32x4){0.f, 0.f, 0.f, 0.f};
    #pragma unroll
    for (int Kt = 0; Kt < 4; ++Kt) {
        short8 bf = *(const short8*)&f2s[w][(Kt * 64 + l) * 8];
        #pragma unroll
        for (int Ma = 0; Ma < 4; ++Ma) {
            short8 af = *(const short8*)&WATs[((Ma * 4 + Kt) * 64 + l) * 8];
            C2[Ma] = __builtin_amdgcn_mfma_f32_16x16x32_bf16(af, bf, C2[Ma], 0, 0, 0);
        }
        short8 itf = {0, 0, 0, 0, 0, 0, 0, 0};
        if (c == 0) {
            float4 i0 = *(const float4*)&iidL[Kt * 32 + g * 8];
            float4 i1 = *(const float4*)&iidL[Kt * 32 + g * 8 + 4];
            itf[0] = f2bf(i0.x); itf[1] = f2bf(i0.y);
            itf[2] = f2bf(i0.z); itf[3] = f2bf(i0.w);
            itf[4] = f2bf(i1.x); itf[5] = f2bf(i1.y);
            itf[6] = f2bf(i1.z); itf[7] = f2bf(i1.w);
        }
        C3 = __builtin_amdgcn_mfma_f32_16x16x32_bf16(itf, bf, C3, 0, 0, 0);
    }

    float psum = 0.f;
    #pragma unroll
    for (int Ma = 0; Ma < 4; ++Ma) {
        float4 ba4 = *(const float4*)&baL[Ma * 16 + g * 4];
        float4 uo4 = *(const float4*)&uoL[Ma * 16 + g * 4];
        psum += fmaxf(C2[Ma][0] + ba4.x, 0.f) * uo4.x;
        psum += fmaxf(C2[Ma][1] + ba4.y, 0.f) * uo4.y;
        psum += fmaxf(C2[Ma][2] + ba4.z, 0.f) * uo4.z;
        psum += fmaxf(C2[Ma][3] + ba4.w, 0.f) * uo4.w;
    }
    psum += __shfl_xor(psum, 16, 64);
    psum += __shfl_xor(psum, 32, 64);
    const float jv = (fn > 0.f) ? __expf(psum) : 0.f;
    const float jy = jv * C3[0];
    float sj = waveReduceSum((g == 0) ? jv : 0.f);
    float sy = waveReduceSum(jy);
    if (l == 0) { sjW[w] = sj; syW[w] = sy; }
    __syncthreads();

    if (w == 0) {
        float s = uidL[l] * iidL[l] + uidL[l + 64] * iidL[l + 64];
        s = waveReduceSum(s);
        if (l == 0) {
            float Sj = sjW[0] + sjW[1] + sjW[2] + sjW[3] + 1e-8f;
            float Sy = syW[0] + syW[1] + syW[2] + syW[3];
            out[b] = s + Sy / Sj + i_bias[ii];
        }
    }
}

extern "C" void kernel_launch(void* const* d_in, const int* in_sizes, int n_in,
                              void* d_out, int out_size, void* d_ws, size_t ws_size,
                              hipStream_t stream)
{
    const int*   input_u  = (const int*)d_in[0];
    const int*   input_i  = (const int*)d_in[1];
    const int*   input_uf = (const int*)d_in[2];
    const float* uidW     = (const float*)d_in[3];
    const float* iidW     = (const float*)d_in[4];
    const float* i_bias   = (const float*)d_in[5];
    const float* Key      = (const float*)d_in[6];
    const float* Mem      = (const float*)d_in[7];
    const float* WA       = (const float*)d_in[8];
    const float* BA       = (const float*)d_in[9];
    const float* U_om     = (const float*)d_in[10];

    const int B = in_sizes[0];
    const int user_num = in_sizes[3] / EDIM - 1;

    float* att = (float*)d_ws;                       // B*400
    float* Pm  = att + (size_t)B * NCOL;             // 16*400
    float* Ps  = Pm + 16 * NCOL;                     // 16*400
    short* WATf  = (short*)(Ps + 16 * NCOL);         // 16*64*8
    short* MemTf = WATf + 16 * 64 * 8;               // 8*64*8
    short* KeyTf = MemTf + 8 * 64 * 8;               // 4*64*8

    k0_prep<<<7, 256, 0, stream>>>(WA, Mem, Key, WATf, MemTf, KeyTf);
    k1_attkey<<<B, 256, 0, stream>>>(input_u, input_uf, uidW, KeyTf, att, user_num);
    k2a_stats<<<dim3(25, 16), 256, 0, stream>>>(att, Pm, Ps, B);
    k3_final<<<B, 256, 0, stream>>>(input_u, input_i, input_uf, uidW, iidW, i_bias,
                                    WATf, MemTf, BA, U_om, att, Pm, Ps,
                                    (float*)d_out, user_num);
}